// Round 2
// baseline (866.894 us; speedup 1.0000x reference)
//
#include <hip/hip_runtime.h>

constexpr int Bc = 32;     // batch
constexpr int Tc = 1000;   // time
constexpr int Vc = 1024;   // vocab
constexpr int Lc = 128;    // label length
constexpr int Sc = 2 * Lc + 1;  // 257 lattice states
constexpr int SP = 320;         // padded stride: 5 states/lane * 64 lanes
constexpr float NEGF = -1e30f;  // matches reference NEG surrogate

// ---------------------------------------------------------------------------
// Kernel A: per (b,t) log-softmax + gather LOG-probs at extended-label states.
// Faithful: precise expf/logf, log-domain output, padding states = NEG.
// ---------------------------------------------------------------------------
__global__ __launch_bounds__(256) void ctc_lse_gather(
    const float* __restrict__ hs, const int* __restrict__ ys,
    float* __restrict__ lpe) {
  const int bt = blockIdx.x;          // b*Tc + t
  const int b = bt / Tc;
  const int tid = threadIdx.x;
  const float* row = hs + (size_t)bt * Vc;

  __shared__ float xs[Vc];
  __shared__ float red[8];

  float4 v = reinterpret_cast<const float4*>(row)[tid];  // 256*4 = 1024
  reinterpret_cast<float4*>(xs)[tid] = v;

  // block max
  float m = fmaxf(fmaxf(v.x, v.y), fmaxf(v.z, v.w));
#pragma unroll
  for (int off = 32; off; off >>= 1) m = fmaxf(m, __shfl_xor(m, off, 64));
  const int wid = tid >> 6;
  if ((tid & 63) == 0) red[wid] = m;
  __syncthreads();
  m = fmaxf(fmaxf(red[0], red[1]), fmaxf(red[2], red[3]));

  // block sum of exp (precise expf)
  float sum = expf(v.x - m) + expf(v.y - m) + expf(v.z - m) + expf(v.w - m);
#pragma unroll
  for (int off = 32; off; off >>= 1) sum += __shfl_xor(sum, off, 64);
  if ((tid & 63) == 0) red[4 + wid] = sum;
  __syncthreads();
  sum = red[4] + red[5] + red[6] + red[7];
  const float lse = m + logf(sum);

  // gather log-probs: ext[s] = (s odd) ? ys[b][s>>1] : blank(0)
  float* out = lpe + (size_t)bt * SP;
  {
    const int s = tid;  // 0..255
    const int lab = (s & 1) ? ys[b * Lc + (s >> 1)] : 0;
    out[s] = xs[lab] - lse;
  }
  if (tid < SP - 256) {  // s = 256..319
    const int s = 256 + tid;
    out[s] = (s == 256) ? (xs[0] - lse) : NEGF;
  }
}

// logaddexp of three args via max-normalization (reference-faithful in fp32).
__device__ inline float lae3(float x, float y, float z) {
  const float M = fmaxf(fmaxf(x, y), z);
  // If M == NEGF all args are NEG: result = NEG + log(3) == NEG in fp32 (ULP(1e30)~1e23).
  return M + logf(expf(x - M) + expf(y - M) + expf(z - M));
}

// ---------------------------------------------------------------------------
// Kernel B: CTC alpha recursion, LOG DOMAIN, mirroring the reference.
// One wave per batch element; 5 contiguous lattice states per lane.
// ---------------------------------------------------------------------------
__global__ __launch_bounds__(64) void ctc_alpha(
    const float* __restrict__ lpe, const int* __restrict__ ys,
    const int* __restrict__ hlen, const int* __restrict__ ylen,
    float* __restrict__ lossb) {
  const int b = blockIdx.x;
  const int lane = threadIdx.x;
  const float* pb = lpe + (size_t)b * Tc * SP;

  // skip-transition mask: odd label state, s>=3, in range, distinct labels
  bool sk[5];
#pragma unroll
  for (int j = 0; j < 5; ++j) {
    const int s = 5 * lane + j;
    bool v = false;
    if ((s & 1) && s >= 3 && s < Sc) {
      const int y1 = ys[b * Lc + (s >> 1)];
      const int y0 = ys[b * Lc + ((s - 2) >> 1)];
      v = (y1 != y0);  // labels are >=1, so y1 != blank always holds
    }
    sk[j] = v;
  }

  // alpha at t=0: states 0 and 1 only
  float a[5];
#pragma unroll
  for (int j = 0; j < 5; ++j) {
    const int s = 5 * lane + j;
    a[j] = (s == 0) ? pb[0] : ((s == 1) ? pb[1] : NEGF);
  }

  const int Te = min(hlen[b], Tc);
  const float* prow = pb + (size_t)SP + 5 * lane;

  // software pipeline: preload row t, load row t+1 during compute
  float lp[5];
#pragma unroll
  for (int j = 0; j < 5; ++j) lp[j] = prow[j];

  for (int t = 1; t < Te; ++t) {
    float lpn[5];
    if (t + 1 < Te) {
#pragma unroll
      for (int j = 0; j < 5; ++j) lpn[j] = prow[SP + j];
    }
    float am1 = __shfl_up(a[4], 1, 64);  // alpha[s-1] for j=0
    float am2 = __shfl_up(a[3], 1, 64);  // alpha[s-2] for j=0
    if (lane == 0) { am1 = NEGF; am2 = NEGF; }

    float n0 = lae3(a[0], am1, sk[0] ? am2 : NEGF) + lp[0];
    float n1 = lae3(a[1], a[0], sk[1] ? am1 : NEGF) + lp[1];
    float n2 = lae3(a[2], a[1], sk[2] ? a[0] : NEGF) + lp[2];
    float n3 = lae3(a[3], a[2], sk[3] ? a[1] : NEGF) + lp[3];
    float n4 = lae3(a[4], a[3], sk[4] ? a[2] : NEGF) + lp[4];
    a[0] = n0; a[1] = n1; a[2] = n2; a[3] = n3; a[4] = n4;

#pragma unroll
    for (int j = 0; j < 5; ++j) lp[j] = lpn[j];
    prow += SP;
  }

  // final: loss = -logaddexp(alpha[2L], alpha[2L-1]) / ylen
  __shared__ float ash[SP];
#pragma unroll
  for (int j = 0; j < 5; ++j) ash[5 * lane + j] = a[j];
  __syncthreads();
  if (lane == 0) {
    const int yl = ylen[b];
    const float x = ash[2 * yl];
    const float y = ash[2 * yl - 1];
    const float M = fmaxf(x, y);
    const float ae = M + logf(expf(x - M) + expf(y - M));
    lossb[b] = -ae / (float)yl;
  }
}

// ---------------------------------------------------------------------------
// Kernel C: mean over batch
// ---------------------------------------------------------------------------
__global__ __launch_bounds__(64) void ctc_final(
    const float* __restrict__ lossb, float* __restrict__ out) {
  const int lane = threadIdx.x;
  float v = (lane < Bc) ? lossb[lane] : 0.f;
#pragma unroll
  for (int off = 32; off; off >>= 1) v += __shfl_xor(v, off, 64);
  if (lane == 0) out[0] = v * (1.f / (float)Bc);
}

extern "C" void kernel_launch(void* const* d_in, const int* in_sizes, int n_in,
                              void* d_out, int out_size, void* d_ws, size_t ws_size,
                              hipStream_t stream) {
  const float* hs = (const float*)d_in[0];    // (B,T,V) fp32
  const int* hlen = (const int*)d_in[1];      // (B,)
  const int* ys = (const int*)d_in[2];        // (B,L)
  const int* ylen = (const int*)d_in[3];      // (B,)
  float* out = (float*)d_out;                 // scalar

  float* lpe = (float*)d_ws;                             // B*T*SP floats (~41 MB)
  float* lossb = lpe + (size_t)Bc * Tc * SP;             // B floats

  ctc_lse_gather<<<Bc * Tc, 256, 0, stream>>>(hs, ys, lpe);
  ctc_alpha<<<Bc, 64, 0, stream>>>(lpe, ys, hlen, ylen, lossb);
  ctc_final<<<1, 64, 0, stream>>>(lossb, out);
}

// Round 3
// 446.268 us; speedup vs baseline: 1.9425x; 1.9425x over previous
//
#include <hip/hip_runtime.h>

constexpr int Bc = 32;     // batch
constexpr int Tc = 1000;   // time
constexpr int Vc = 1024;   // vocab
constexpr int Lc = 128;    // label length
constexpr int Sc = 2 * Lc + 1;  // 257 lattice states
constexpr int SP = 320;         // padded stride: 5 states/lane * 64 lanes
constexpr float NEGF = -1e30f;  // log-space -inf surrogate (reference NEG)
constexpr float L2E = 1.4426950408889634f;   // log2(e)
constexpr float LN2 = 0.6931471805599453f;   // ln(2)

#if __has_builtin(__builtin_amdgcn_exp2f)
#define EXP2F(x) __builtin_amdgcn_exp2f(x)
#else
#define EXP2F(x) exp2f(x)
#endif
#if __has_builtin(__builtin_amdgcn_logf)
#define LOG2F(x) __builtin_amdgcn_logf(x)
#else
#define LOG2F(x) log2f(x)
#endif
#if __has_builtin(__builtin_amdgcn_fmed3f)
#define MED3F(x, y, z) __builtin_amdgcn_fmed3f(x, y, z)
#else
#define MED3F(x, y, z) fmaxf(fminf(fmaxf(x, y), z), fminf(x, y))
#endif

// ---------------------------------------------------------------------------
// Kernel A: per (b,t) log-softmax + gather, all in log2 domain.
// Output lp2[s] = (x[ext[s]] - lse) * log2(e); padding states = NEGF.
// ---------------------------------------------------------------------------
__global__ __launch_bounds__(256) void ctc_lse_gather(
    const float* __restrict__ hs, const int* __restrict__ ys,
    float* __restrict__ lpe) {
  const int bt = blockIdx.x;          // b*Tc + t
  const int b = bt / Tc;
  const int tid = threadIdx.x;
  const float* row = hs + (size_t)bt * Vc;

  __shared__ float xs[Vc];            // logits pre-scaled by log2(e)
  __shared__ float red[8];

  float4 v = reinterpret_cast<const float4*>(row)[tid];  // 256*4 = 1024
  v.x *= L2E; v.y *= L2E; v.z *= L2E; v.w *= L2E;
  reinterpret_cast<float4*>(xs)[tid] = v;

  // block max (log2 domain)
  float m = fmaxf(fmaxf(v.x, v.y), fmaxf(v.z, v.w));
#pragma unroll
  for (int off = 32; off; off >>= 1) m = fmaxf(m, __shfl_xor(m, off, 64));
  const int wid = tid >> 6;
  if ((tid & 63) == 0) red[wid] = m;
  __syncthreads();
  m = fmaxf(fmaxf(red[0], red[1]), fmaxf(red[2], red[3]));

  // block sum of exp2
  float sum = EXP2F(v.x - m) + EXP2F(v.y - m) + EXP2F(v.z - m) + EXP2F(v.w - m);
#pragma unroll
  for (int off = 32; off; off >>= 1) sum += __shfl_xor(sum, off, 64);
  if ((tid & 63) == 0) red[4 + wid] = sum;
  __syncthreads();
  sum = red[4] + red[5] + red[6] + red[7];
  const float lse2 = m + LOG2F(sum);

  // gather log2-probs: ext[s] = (s odd) ? ys[b][s>>1] : blank(0)
  float* out = lpe + (size_t)bt * SP;
  {
    const int s = tid;  // 0..255
    const int lab = (s & 1) ? ys[b * Lc + (s >> 1)] : 0;
    out[s] = xs[lab] - lse2;
  }
  if (tid < SP - 256) {  // s = 256..319
    const int s = 256 + tid;
    out[s] = (s == 256) ? (xs[0] - lse2) : NEGF;
  }
}

// Sorted 3-way logaddexp in log2 domain: exp2 of the max term is exactly 1,
// so only 2 exp2 + 1 log2 per call (v_max3/v_med3/v_min3 are full-rate VALU).
__device__ inline float lae3(float x, float y, float z) {
  const float M = fmaxf(fmaxf(x, y), z);
  const float md = MED3F(x, y, z);
  const float mn = fminf(fminf(x, y), z);
  const float s = 1.f + EXP2F(md - M) + EXP2F(mn - M);
  return M + LOG2F(s);
}

// ---------------------------------------------------------------------------
// Kernel B: CTC alpha recursion, log2 domain, one wave per batch element,
// 5 contiguous lattice states per lane, double-buffered 8-row prefetch.
// ---------------------------------------------------------------------------
__global__ __launch_bounds__(64) void ctc_alpha(
    const float* __restrict__ lpe, const int* __restrict__ ys,
    const int* __restrict__ hlen, const int* __restrict__ ylen,
    float* __restrict__ lossb) {
  const int b = blockIdx.x;
  const int lane = threadIdx.x;
  const float* pb = lpe + (size_t)b * Tc * SP;

  // skip-transition mask: odd label state, s>=3, in range, distinct labels
  bool sk[5];
#pragma unroll
  for (int j = 0; j < 5; ++j) {
    const int s = 5 * lane + j;
    bool vv = false;
    if ((s & 1) && s >= 3 && s < Sc) {
      const int y1 = ys[b * Lc + (s >> 1)];
      const int y0 = ys[b * Lc + ((s - 2) >> 1)];
      vv = (y1 != y0);  // labels >=1, so y1 != blank always
    }
    sk[j] = vv;
  }

  // alpha at t=0 (log2 domain): states 0 and 1 only
  float a[5];
#pragma unroll
  for (int j = 0; j < 5; ++j) {
    const int s = 5 * lane + j;
    a[j] = (s == 0) ? pb[0] : ((s == 1) ? pb[1] : NEGF);
  }

  const int Te = min(hlen[b], Tc);
  const float* prow = pb + (size_t)SP + 5 * lane;  // row t=1, this lane's 5 states

  float pr[2][8][5];
  int t = 1;
  int cur = 0;
  if (t + 8 <= Te) {
#pragma unroll
    for (int k = 0; k < 8; ++k)
#pragma unroll
      for (int j = 0; j < 5; ++j) pr[0][k][j] = prow[k * SP + j];
  }

  while (t + 8 <= Te) {
    const int nxt = cur ^ 1;
    if (t + 16 <= Te) {  // prefetch next chunk while computing this one
#pragma unroll
      for (int k = 0; k < 8; ++k)
#pragma unroll
        for (int j = 0; j < 5; ++j) pr[nxt][k][j] = prow[(8 + k) * SP + j];
    }
#pragma unroll
    for (int k = 0; k < 8; ++k) {
      float am1 = __shfl_up(a[4], 1, 64);  // alpha[s-1] for j=0
      float am2 = __shfl_up(a[3], 1, 64);  // alpha[s-2] for j=0
      if (lane == 0) { am1 = NEGF; am2 = NEGF; }
      const float n0 = lae3(a[0], am1, sk[0] ? am2 : NEGF) + pr[cur][k][0];
      const float n1 = lae3(a[1], a[0], sk[1] ? am1 : NEGF) + pr[cur][k][1];
      const float n2 = lae3(a[2], a[1], sk[2] ? a[0] : NEGF) + pr[cur][k][2];
      const float n3 = lae3(a[3], a[2], sk[3] ? a[1] : NEGF) + pr[cur][k][3];
      const float n4 = lae3(a[4], a[3], sk[4] ? a[2] : NEGF) + pr[cur][k][4];
      a[0] = n0; a[1] = n1; a[2] = n2; a[3] = n3; a[4] = n4;
    }
    t += 8;
    prow += 8 * SP;
    cur = nxt;
  }

  // tail steps (<8)
  while (t < Te) {
    float lp[5];
#pragma unroll
    for (int j = 0; j < 5; ++j) lp[j] = prow[j];
    float am1 = __shfl_up(a[4], 1, 64);
    float am2 = __shfl_up(a[3], 1, 64);
    if (lane == 0) { am1 = NEGF; am2 = NEGF; }
    const float n0 = lae3(a[0], am1, sk[0] ? am2 : NEGF) + lp[0];
    const float n1 = lae3(a[1], a[0], sk[1] ? am1 : NEGF) + lp[1];
    const float n2 = lae3(a[2], a[1], sk[2] ? a[0] : NEGF) + lp[2];
    const float n3 = lae3(a[3], a[2], sk[3] ? a[1] : NEGF) + lp[3];
    const float n4 = lae3(a[4], a[3], sk[4] ? a[2] : NEGF) + lp[4];
    a[0] = n0; a[1] = n1; a[2] = n2; a[3] = n3; a[4] = n4;
    ++t;
    prow += SP;
  }

  // final: loss = -ln2 * logaddexp2(alpha[2L], alpha[2L-1]) / ylen
  __shared__ float ash[SP];
#pragma unroll
  for (int j = 0; j < 5; ++j) ash[5 * lane + j] = a[j];
  __syncthreads();
  if (lane == 0) {
    const int yl = ylen[b];
    const float x = ash[2 * yl];
    const float y = ash[2 * yl - 1];
    const float M = fmaxf(x, y);
    const float ae2 = M + LOG2F(EXP2F(x - M) + EXP2F(y - M));
    lossb[b] = -(ae2 * LN2) / (float)yl;
  }
}

// ---------------------------------------------------------------------------
// Kernel C: mean over batch
// ---------------------------------------------------------------------------
__global__ __launch_bounds__(64) void ctc_final(
    const float* __restrict__ lossb, float* __restrict__ out) {
  const int lane = threadIdx.x;
  float v = (lane < Bc) ? lossb[lane] : 0.f;
#pragma unroll
  for (int off = 32; off; off >>= 1) v += __shfl_xor(v, off, 64);
  if (lane == 0) out[0] = v * (1.f / (float)Bc);
}

extern "C" void kernel_launch(void* const* d_in, const int* in_sizes, int n_in,
                              void* d_out, int out_size, void* d_ws, size_t ws_size,
                              hipStream_t stream) {
  const float* hs = (const float*)d_in[0];    // (B,T,V) fp32
  const int* hlen = (const int*)d_in[1];      // (B,)
  const int* ys = (const int*)d_in[2];        // (B,L)
  const int* ylen = (const int*)d_in[3];      // (B,)
  float* out = (float*)d_out;                 // scalar

  float* lpe = (float*)d_ws;                             // B*T*SP floats (~41 MB)
  float* lossb = lpe + (size_t)Bc * Tc * SP;             // B floats

  ctc_lse_gather<<<Bc * Tc, 256, 0, stream>>>(hs, ys, lpe);
  ctc_alpha<<<Bc, 64, 0, stream>>>(lpe, ys, hlen, ylen, lossb);
  ctc_final<<<1, 64, 0, stream>>>(lossb, out);
}

// Round 4
// 388.204 us; speedup vs baseline: 2.2331x; 1.1496x over previous
//
#include <hip/hip_runtime.h>

constexpr int Bc = 32;     // batch
constexpr int Tc = 1000;   // time
constexpr int Vc = 1024;   // vocab
constexpr int Lc = 128;    // label length
constexpr int Sc = 2 * Lc + 1;  // 257 lattice states
constexpr int SP = 320;         // padded stride: 5 states/lane * 64 lanes
constexpr float NEGF = -1e30f;  // log-space -inf surrogate (reference NEG)
constexpr float L2E = 1.4426950408889634f;   // log2(e)
constexpr float LN2 = 0.6931471805599453f;   // ln(2)

#if __has_builtin(__builtin_amdgcn_exp2f)
#define EXP2F(x) __builtin_amdgcn_exp2f(x)
#else
#define EXP2F(x) exp2f(x)
#endif
#if __has_builtin(__builtin_amdgcn_logf)
#define LOG2F(x) __builtin_amdgcn_logf(x)
#else
#define LOG2F(x) log2f(x)
#endif
#if __has_builtin(__builtin_amdgcn_fmed3f)
#define MED3F(x, y, z) __builtin_amdgcn_fmed3f(x, y, z)
#else
#define MED3F(x, y, z) fmaxf(fminf(fmaxf(x, y), z), fminf(x, y))
#endif

// Interleaved lattice layout: position p = j*64 + lane holds state s = 5*lane + j.
// A's stores and alpha's loads are both fully coalesced under this mapping.

// ---------------------------------------------------------------------------
// Kernel A: log-softmax + gather, one WAVE per (b,t) row (4 waves/block, each
// wave independent: butterfly all-reduce, own LDS region, no block barrier
// needed semantically — one __syncthreads kept as a cheap LDS fence).
// ---------------------------------------------------------------------------
__global__ __launch_bounds__(256) void ctc_lse_gather(
    const float* __restrict__ hs, const int* __restrict__ ys,
    float* __restrict__ lpe) {
  const int wv = threadIdx.x >> 6;
  const int lane = threadIdx.x & 63;
  const int bt = blockIdx.x * 4 + wv;   // row index b*Tc + t
  const int b = bt / Tc;
  const float* row = hs + (size_t)bt * Vc;

  __shared__ float xs_all[4][Vc];
  float* xs = xs_all[wv];

  // 16 logits per lane, coalesced float4 loads; pre-scale by log2(e)
  float4 v[4];
#pragma unroll
  for (int q = 0; q < 4; ++q) v[q] = reinterpret_cast<const float4*>(row)[lane + 64 * q];
#pragma unroll
  for (int q = 0; q < 4; ++q) { v[q].x *= L2E; v[q].y *= L2E; v[q].z *= L2E; v[q].w *= L2E; }

  // wave all-reduce max (butterfly)
  float m = -3.4e38f;
#pragma unroll
  for (int q = 0; q < 4; ++q)
    m = fmaxf(m, fmaxf(fmaxf(v[q].x, v[q].y), fmaxf(v[q].z, v[q].w)));
#pragma unroll
  for (int off = 32; off; off >>= 1) m = fmaxf(m, __shfl_xor(m, off, 64));

  // wave all-reduce sum of exp2
  float sum = 0.f;
#pragma unroll
  for (int q = 0; q < 4; ++q)
    sum += EXP2F(v[q].x - m) + EXP2F(v[q].y - m) + EXP2F(v[q].z - m) + EXP2F(v[q].w - m);
#pragma unroll
  for (int off = 32; off; off >>= 1) sum += __shfl_xor(sum, off, 64);
  const float lse2 = m + LOG2F(sum);

  // stage scaled logits for the label gather
#pragma unroll
  for (int q = 0; q < 4; ++q) reinterpret_cast<float4*>(xs)[lane + 64 * q] = v[q];
  __syncthreads();  // LDS fence (waves independent; cheap)

  // gather log2-probs into interleaved layout
  float* out = lpe + (size_t)bt * SP;
#pragma unroll
  for (int j = 0; j < 5; ++j) {
    const int s = 5 * lane + j;
    float val = NEGF;
    if (s < Sc) {
      const int lab = (s & 1) ? ys[b * Lc + (s >> 1)] : 0;
      val = xs[lab] - lse2;
    }
    out[j * 64 + lane] = val;  // coalesced 256B store per j
  }
}

// Sorted 3-way logaddexp in log2 domain: exp2 of the max term is exactly 1,
// so only 2 exp2 + 1 log2 per call (max3/med3/min3 are full-rate VALU).
__device__ inline float lae3(float x, float y, float z) {
  const float M = fmaxf(fmaxf(x, y), z);
  const float md = MED3F(x, y, z);
  const float mn = fminf(fminf(x, y), z);
  const float s = 1.f + EXP2F(md - M) + EXP2F(mn - M);
  return M + LOG2F(s);
}

// ---------------------------------------------------------------------------
// Kernel B: CTC alpha recursion, log2 domain, one wave per batch element,
// 5 states per lane (interleaved layout), STATIC ping-pong 8-row prefetch
// (no dynamic register-array indexing — stays in VGPRs, no scratch).
// ---------------------------------------------------------------------------
__global__ __launch_bounds__(64) void ctc_alpha(
    const float* __restrict__ lpe, const int* __restrict__ ys,
    const int* __restrict__ hlen, const int* __restrict__ ylen,
    float* __restrict__ lossb) {
  const int b = blockIdx.x;
  const int lane = threadIdx.x;
  const float* pb = lpe + (size_t)b * Tc * SP;

  // skip-transition mask
  bool sk[5];
#pragma unroll
  for (int j = 0; j < 5; ++j) {
    const int s = 5 * lane + j;
    bool vv = false;
    if ((s & 1) && s >= 3 && s < Sc) {
      const int y1 = ys[b * Lc + (s >> 1)];
      const int y0 = ys[b * Lc + ((s - 2) >> 1)];
      vv = (y1 != y0);  // labels >=1, so y1 != blank always
    }
    sk[j] = vv;
  }

  // alpha at t=0: state 0 at pos 0, state 1 at pos 64 (interleaved layout)
  float a[5];
#pragma unroll
  for (int j = 0; j < 5; ++j) {
    const int s = 5 * lane + j;
    a[j] = (s == 0) ? pb[0] : ((s == 1) ? pb[64] : NEGF);
  }

  const int Te = min(hlen[b], Tc);

  auto step = [&](const float* lp) {
    float am1 = __shfl_up(a[4], 1, 64);  // alpha[s-1] for j=0
    float am2 = __shfl_up(a[3], 1, 64);  // alpha[s-2] for j=0
    if (lane == 0) { am1 = NEGF; am2 = NEGF; }
    const float n0 = lae3(a[0], am1, sk[0] ? am2 : NEGF) + lp[0];
    const float n1 = lae3(a[1], a[0], sk[1] ? am1 : NEGF) + lp[1];
    const float n2 = lae3(a[2], a[1], sk[2] ? a[0] : NEGF) + lp[2];
    const float n3 = lae3(a[3], a[2], sk[3] ? a[1] : NEGF) + lp[3];
    const float n4 = lae3(a[4], a[3], sk[4] ? a[2] : NEGF) + lp[4];
    a[0] = n0; a[1] = n1; a[2] = n2; a[3] = n3; a[4] = n4;
  };

  float bufA[8][5], bufB[8][5];
  auto load8A = [&](int trow) {
    const float* p = pb + (size_t)trow * SP + lane;
#pragma unroll
    for (int k = 0; k < 8; ++k)
#pragma unroll
      for (int j = 0; j < 5; ++j) bufA[k][j] = p[k * SP + j * 64];
  };
  auto load8B = [&](int trow) {
    const float* p = pb + (size_t)trow * SP + lane;
#pragma unroll
    for (int k = 0; k < 8; ++k)
#pragma unroll
      for (int j = 0; j < 5; ++j) bufB[k][j] = p[k * SP + j * 64];
  };

  int t = 1;
  if (t + 8 <= Te) load8A(t);
  while (t + 16 <= Te) {
    load8B(t + 8);
#pragma unroll
    for (int k = 0; k < 8; ++k) step(bufA[k]);
    t += 8;
    if (t + 16 <= Te) load8A(t + 8);
#pragma unroll
    for (int k = 0; k < 8; ++k) step(bufB[k]);
    t += 8;
  }
  if (t + 8 <= Te) {  // bufA holds rows t..t+7 on every path reaching here
#pragma unroll
    for (int k = 0; k < 8; ++k) step(bufA[k]);
    t += 8;
  }
  while (t < Te) {  // tail (<8 rows)
    float lp[5];
#pragma unroll
    for (int j = 0; j < 5; ++j) lp[j] = pb[(size_t)t * SP + j * 64 + lane];
    step(lp);
    ++t;
  }

  // final: loss = -ln2 * logaddexp2(alpha[2L], alpha[2L-1]) / ylen
  __shared__ float ash[SP];
#pragma unroll
  for (int j = 0; j < 5; ++j) ash[5 * lane + j] = a[j];
  __syncthreads();
  if (lane == 0) {
    const int yl = ylen[b];
    const float x = ash[2 * yl];
    const float y = ash[2 * yl - 1];
    const float M = fmaxf(x, y);
    const float ae2 = M + LOG2F(EXP2F(x - M) + EXP2F(y - M));
    lossb[b] = -(ae2 * LN2) / (float)yl;
  }
}

// ---------------------------------------------------------------------------
// Kernel C: mean over batch
// ---------------------------------------------------------------------------
__global__ __launch_bounds__(64) void ctc_final(
    const float* __restrict__ lossb, float* __restrict__ out) {
  const int lane = threadIdx.x;
  float v = (lane < Bc) ? lossb[lane] : 0.f;
#pragma unroll
  for (int off = 32; off; off >>= 1) v += __shfl_xor(v, off, 64);
  if (lane == 0) out[0] = v * (1.f / (float)Bc);
}

extern "C" void kernel_launch(void* const* d_in, const int* in_sizes, int n_in,
                              void* d_out, int out_size, void* d_ws, size_t ws_size,
                              hipStream_t stream) {
  const float* hs = (const float*)d_in[0];    // (B,T,V) fp32
  const int* hlen = (const int*)d_in[1];      // (B,)
  const int* ys = (const int*)d_in[2];        // (B,L)
  const int* ylen = (const int*)d_in[3];      // (B,)
  float* out = (float*)d_out;                 // scalar

  float* lpe = (float*)d_ws;                             // B*T*SP floats (~41 MB)
  float* lossb = lpe + (size_t)Bc * Tc * SP;             // B floats

  ctc_lse_gather<<<Bc * Tc / 4, 256, 0, stream>>>(hs, ys, lpe);
  ctc_alpha<<<Bc, 64, 0, stream>>>(lpe, ys, hlen, ylen, lossb);
  ctc_final<<<1, 64, 0, stream>>>(lossb, out);
}